// Round 4
// baseline (791.777 us; speedup 1.0000x reference)
//
#include <hip/hip_runtime.h>
#include <math.h>

namespace {

constexpr int kH = 500, kW = 500, kNV = 5023, kNF = 9976, kB = 2;
constexpr float kFocal = 1015.0f;
constexpr float kEps = 1e-6f;
constexpr int kNB = 8;                       // z buckets per tile
constexpr unsigned kListCap = 1900000u;      // u16 entries (expected ~860k)

// ---------------------------------------------------------------- utilities
__device__ inline void cross3(float ax, float ay, float az,
                              float bx, float by, float bz,
                              float& cx, float& cy, float& cz) {
  cx = ay * bz - az * by;
  cy = az * bx - ax * bz;
  cz = ax * by - ay * bx;
}

// Edge-separation triangle-vs-tile cull. MUST be bit-identical between count
// and fill passes (shared fn, same inputs -> deterministic counts).
__device__ inline bool tileCull(const float4 r0, const float4 r1,
                                float tX0, float tX1, float tY0, float tY1) {
  float hi0 = fmaf(r0.x, r0.x >= 0.f ? tX1 : tX0,
                   fmaf(r0.y, r0.y >= 0.f ? tY1 : tY0, r0.z));
  float lo0 = fmaf(r0.x, r0.x >= 0.f ? tX0 : tX1,
                   fmaf(r0.y, r0.y >= 0.f ? tY0 : tY1, r0.z));
  float hi1 = fmaf(r1.x, r1.x >= 0.f ? tX1 : tX0,
                   fmaf(r1.y, r1.y >= 0.f ? tY1 : tY0, r1.z));
  float lo1 = fmaf(r1.x, r1.x >= 0.f ? tX0 : tX1,
                   fmaf(r1.y, r1.y >= 0.f ? tY0 : tY1, r1.z));
  float m2 = 2.f * r0.w;   // looser than the per-pixel margin -mw: conservative
  return hi0 >= -m2 && hi1 >= -m2 && (1.f - lo0 - lo1) >= -m2;
}

__device__ inline int bucketOf(float zminf, float zlo, float iscale) {
  float t = (zminf - zlo) * iscale;
  t = fminf(fmaxf(t, 0.f), (float)(kNB - 1));   // fmaxf(nan,0)=0 -> safe
  return (int)t;
}

// ---------------------------------------------------------------- kernels
__global__ void init_k(float* nacc, unsigned* cnt, unsigned* zr) {
  int i = blockIdx.x * 256 + threadIdx.x;
  if (i < kB * kNV * 3) nacc[i] = 0.0f;
  if (i < kB * 32 * 32 * kNB) cnt[i] = 0u;
  if (i < 2 * kB) zr[i] = (i & 1) ? 0u : 0x7F800000u;  // {min=+inf, max=0} bits
}

__global__ void normal_accum_k(const float* __restrict__ verts,
                               const int* __restrict__ faces,
                               float* __restrict__ nacc) {
  int idx = blockIdx.x * 256 + threadIdx.x;
  if (idx >= kB * kNF) return;
  int b = idx / kNF, f = idx - b * kNF;
  int i0 = faces[3 * f + 0], i1 = faces[3 * f + 1], i2 = faces[3 * f + 2];
  const float* vb = verts + (size_t)b * kNV * 3;
  float x0 = vb[3 * i0], y0 = vb[3 * i0 + 1], z0 = vb[3 * i0 + 2];
  float x1 = vb[3 * i1], y1 = vb[3 * i1 + 1], z1 = vb[3 * i1 + 2];
  float x2 = vb[3 * i2], y2 = vb[3 * i2 + 1], z2 = vb[3 * i2 + 2];
  float* nb = nacc + (size_t)b * kNV * 3;
  float cx, cy, cz;
  cross3(x2 - x1, y2 - y1, z2 - z1, x0 - x1, y0 - y1, z0 - z1, cx, cy, cz);
  atomicAdd(nb + 3 * i1 + 0, cx);
  atomicAdd(nb + 3 * i1 + 1, cy);
  atomicAdd(nb + 3 * i1 + 2, cz);
  cross3(x0 - x2, y0 - y2, z0 - z2, x1 - x2, y1 - y2, z1 - z2, cx, cy, cz);
  atomicAdd(nb + 3 * i2 + 0, cx);
  atomicAdd(nb + 3 * i2 + 1, cy);
  atomicAdd(nb + 3 * i2 + 2, cz);
  cross3(x1 - x0, y1 - y0, z1 - z0, x2 - x0, y2 - y0, z2 - z0, cx, cy, cz);
  atomicAdd(nb + 3 * i0 + 0, cx);
  atomicAdd(nb + 3 * i0 + 1, cy);
  atomicAdd(nb + 3 * i0 + 2, cz);
}

__global__ void proj_norm_k(const float* __restrict__ verts,
                            float* __restrict__ nacc,
                            float4* __restrict__ proj) {
  int idx = blockIdx.x * 256 + threadIdx.x;
  if (idx >= kB * kNV) return;
  float nx = nacc[3 * idx + 0], ny = nacc[3 * idx + 1], nz = nacc[3 * idx + 2];
  float nn = sqrtf(nx * nx + ny * ny + nz * nz);
  float nd = fmaxf(nn, kEps);
  nacc[3 * idx + 0] = nx / nd;
  nacc[3 * idx + 1] = ny / nd;
  nacc[3 * idx + 2] = nz / nd;
  float vx = verts[3 * idx + 0], vy = verts[3 * idx + 1], vz = verts[3 * idx + 2];
  float xc = -vx, yc = vy, zc = -vz;
  float zs = fmaxf(zc, kEps);
  float px = __fsub_rn(0.5f * kW, __fdiv_rn(__fmul_rn(kFocal, xc), zs));
  float py = __fsub_rn(0.5f * kH, __fdiv_rn(__fmul_rn(kFocal, yc), zs));
  proj[idx] = make_float4(px, py, zc, 0.0f);
}

// fdE (3 float4): {cx,cy,A0,B0} {A1,B1,den,za} {zb,zc,0,0}   (exact path)
// fdP (3 float4): {P0,Q0,R0,mw} {P1,Q1,R1,mz} {Zx,Zy,Zc,zminf} (prefilter)
// fdB (1 float4): bbox {minx,maxx,miny,maxy}, inf-sentinel if invalid
__global__ void face_setup_k(const float4* __restrict__ proj,
                             const int* __restrict__ faces,
                             float4* __restrict__ fdE,
                             float4* __restrict__ fdP,
                             float4* __restrict__ fdB,
                             unsigned* __restrict__ zr) {
  int idx = blockIdx.x * 256 + threadIdx.x;
  if (idx >= kB * kNF) return;
  int b = idx / kNF, f = idx - b * kNF;
  int i0 = faces[3 * f + 0], i1 = faces[3 * f + 1], i2 = faces[3 * f + 2];
  float4 A = proj[b * kNV + i0];
  float4 Bv = proj[b * kNV + i1];
  float4 C = proj[b * kNV + i2];
  float ax = A.x, ay = A.y, za = A.z;
  float bx = Bv.x, by = Bv.y, zb = Bv.z;
  float cx = C.x, cy = C.y, zc = C.z;
  float A0 = __fsub_rn(by, cy);
  float B0 = __fsub_rn(cx, bx);
  float A1 = __fsub_rn(cy, ay);
  float B1 = __fsub_rn(ax, cx);
  float e = __fsub_rn(ay, cy);
  float den = __fadd_rn(__fmul_rn(A0, B1), __fmul_rn(B0, e));
  bool valid = (fabsf(den) >= kEps) && (za > kEps) && (zb > kEps) && (zc > kEps);
  float ds = valid ? den : 1.0f;

  float4* oe = fdE + (size_t)idx * 3;
  oe[0] = make_float4(cx, cy, A0, B0);
  oe[1] = make_float4(A1, B1, ds, za);
  oe[2] = make_float4(zb, zc, 0.0f, 0.0f);

  float P0 = A0 / ds, Q0 = B0 / ds, R0 = -(A0 * cx + B0 * cy) / ds;
  float P1 = A1 / ds, Q1 = B1 / ds, R1 = -(A1 * cx + B1 * cy) / ds;
  float dza = za - zc, dzb = zb - zc;
  float Zx = dza * P0 + dzb * P1;
  float Zy = dza * Q0 + dzb * Q1;
  float Zc = dza * R0 + dzb * R1 + zc;
  float S0 = (fabsf(P0) + fabsf(Q0)) * 512.f + fabsf(R0);
  float S1 = (fabsf(P1) + fabsf(Q1)) * 512.f + fabsf(R1);
  float Sz = (fabsf(Zx) + fabsf(Zy)) * 512.f + fabsf(Zc);
  float m0 = S0 * 0x1p-18f;
  float m1 = S1 * 0x1p-18f;
  float mw = m0 + m1 + 2e-6f;
  float mz = m0 * fabsf(dza) + m1 * fabsf(dzb) + Sz * 0x1p-18f +
             0x1p-18f * (fabsf(zc) + fabsf(dza) + fabsf(dzb) + 1.f) + 2e-6f;
  float zminf = fminf(fminf(za, zb), zc);

  float4* op = fdP + (size_t)idx * 3;
  op[0] = make_float4(P0, Q0, R0, mw);
  op[1] = make_float4(P1, Q1, R1, mz);
  op[2] = make_float4(Zx, Zy, Zc, zminf);

  float mnx, mxx, mny, mxy;
  if (valid) {
    mnx = fminf(fminf(ax, bx), cx) - 0.5f;
    mxx = fmaxf(fmaxf(ax, bx), cx) + 0.5f;
    mny = fminf(fminf(ay, by), cy) - 0.5f;
    mxy = fmaxf(fmaxf(ay, by), cy) + 0.5f;
    // zminf > eps > 0 for valid faces -> uint bit-pattern preserves order.
    atomicMin(zr + 2 * b + 0, __float_as_uint(zminf));
    atomicMax(zr + 2 * b + 1, __float_as_uint(zminf));
  } else {
    mnx = INFINITY; mxx = -INFINITY; mny = INFINITY; mxy = -INFINITY;
  }
  fdB[idx] = make_float4(mnx, mxx, mny, mxy);
}

// Binning: thread = (face, tile-row, batch). Walks the bbox's tile columns,
// culls, and counts (FILL=0) or appends u16 face idx (FILL=1). cnt doubles as
// the fill cursor (scan pre-sets it to the exclusive offsets).
template <bool FILL>
__global__ void bin_k(const float4* __restrict__ fdP,
                      const float4* __restrict__ fdB,
                      const unsigned* __restrict__ zr,
                      unsigned* __restrict__ cnt,
                      unsigned short* __restrict__ list) {
  int f = blockIdx.x * 256 + threadIdx.x;
  if (f >= kNF) return;
  int b = blockIdx.z, ty = blockIdx.y;
  size_t bOff = (size_t)b * kNF;
  float4 bb = fdB[bOff + f];
  float tY0 = 16.f * ty + 0.5f, tY1 = tY0 + 15.f;
  if (!(bb.z <= tY1 && bb.w >= tY0)) return;
  // Tile-column range covered by bbox (clamped in float to avoid huge-cvt UB).
  float t0f = fminf(fmaxf(ceilf((bb.x - 15.5f) * 0.0625f), 0.f), 31.f);
  float t1f = fminf(fmaxf(floorf((bb.y - 0.5f) * 0.0625f), 0.f), 31.f);
  int tx0 = (int)t0f, tx1 = (int)t1f;
  if (tx0 > tx1) return;
  const float4* rp = fdP + (bOff + f) * 3;
  float4 r0 = rp[0], r1 = rp[1], r2 = rp[2];
  float zlo = __uint_as_float(zr[2 * b]);
  float zhi = __uint_as_float(zr[2 * b + 1]);
  float range = zhi - zlo;
  float iscale = range > 1e-30f ? (float)kNB / range : 0.f;
  int q = bucketOf(r2.w, zlo, iscale);
  for (int tx = tx0; tx <= tx1; ++tx) {
    float tX0 = 16.f * tx + 0.5f, tX1 = tX0 + 15.f;
    if (tileCull(r0, r1, tX0, tX1, tY0, tY1)) {
      unsigned i = (unsigned)((b * 32 + ty) * 32 + tx) * kNB + q;
      if (FILL) {
        unsigned pos = atomicAdd(&cnt[i], 1u);
        if (pos < kListCap) list[pos] = (unsigned short)f;
      } else {
        atomicAdd(&cnt[i], 1u);
      }
    }
  }
}

// Exclusive scan over the 16384 (tile,bucket) counts. Single 256-thread block;
// writes off[] (for raster) and resets cnt[] to the offsets (fill cursors).
__global__ void scan_k(unsigned* __restrict__ cnt, unsigned* __restrict__ off) {
  constexpr int N = kB * 32 * 32 * kNB;   // 16384
  constexpr int PER = N / 256;            // 64
  __shared__ unsigned part[256];
  __shared__ unsigned base[256];
  __shared__ unsigned total;
  int t = threadIdx.x;
  unsigned loc[PER];
  unsigned s = 0;
#pragma unroll
  for (int i = 0; i < PER; ++i) { loc[i] = cnt[t * PER + i]; s += loc[i]; }
  part[t] = s;
  __syncthreads();
  if (t == 0) {
    unsigned r = 0;
    for (int i = 0; i < 256; ++i) { base[i] = r; r += part[i]; }
    total = r;
  }
  __syncthreads();
  unsigned r = base[t];
#pragma unroll
  for (int i = 0; i < PER; ++i) {
    off[t * PER + i] = r;
    cnt[t * PER + i] = r;
    r += loc[i];
  }
  if (t == 0) off[N] = total;
}

// 16x16-pixel tile per block; iterates its pre-binned candidate list bucket by
// bucket (front-to-back), LDS-staging 256 candidates at a time. Early-break
// when ALL pixels' zmin beats the conservative lower bound of later buckets
// (strictly safe: skipped candidates have exact z > zmin, ties impossible).
// Discrete decisions replicate reference fp32 rounding; (z,idx) lex-min is
// order-independent == jnp.argmin first-min. Shading fused.
__global__ __launch_bounds__(256) void raster_k(
    const float4* __restrict__ fdP, const float4* __restrict__ fdE,
    const unsigned* __restrict__ off, const unsigned short* __restrict__ list,
    const unsigned* __restrict__ zr, const float* __restrict__ verts,
    const float* __restrict__ nrm, const int* __restrict__ faces,
    float* __restrict__ out) {
  __shared__ float4 sA[256], sB[256], sC[256];   // 12 KiB
  int b = blockIdx.z;
  size_t bOff = (size_t)b * kNF;
  int tx = threadIdx.x & 15, ty = threadIdx.x >> 4;
  int x = blockIdx.x * 16 + tx;
  int y = blockIdx.y * 16 + ty;
  float xp = (float)x + 0.5f;
  float yp = (float)y + 0.5f;
  bool live = (x < kW && y < kH);
  float zmin = live ? INFINITY : -INFINITY;   // dead px never block the break
  int best = 0x7FFFFFFF;
  float bw0 = 0.f, bw1 = 0.f, bw2 = 0.f;

  float zlo = __uint_as_float(zr[2 * b]);
  float zhi = __uint_as_float(zr[2 * b + 1]);
  float range = zhi - zlo;
  float bwid = range > 1e-30f ? range * (1.f / kNB) : 0.f;
  const unsigned* offT =
      off + (unsigned)((b * 32 + blockIdx.y) * 32 + blockIdx.x) * kNB;

  for (int q = 0; q < kNB; ++q) {
    if (q > 0) {
      float lb = zlo + (float)q * bwid * (1.f - 1e-5f) - 2e-5f;
      if (__syncthreads_and(zmin < lb)) break;
    }
    unsigned s = offT[q], e = offT[q + 1];
    for (unsigned base = s; base < e; base += 256) {
      int n = min(256u, e - base);
      __syncthreads();
      if ((int)threadIdx.x < n) {
        unsigned fi = list[base + threadIdx.x];
        const float4* rp = fdP + (bOff + fi) * 3;
        float4 r0 = rp[0], r1 = rp[1], r2 = rp[2];
        r2.w = __int_as_float((int)fi);
        sA[threadIdx.x] = r0;
        sB[threadIdx.x] = r1;
        sC[threadIdx.x] = r2;
      }
      __syncthreads();
      for (int k = 0; k < n; ++k) {
        float4 a = sA[k], bq = sB[k], c = sC[k];
        float w0a = fmaf(a.x, xp, fmaf(a.y, yp, a.z));
        float w1a = fmaf(bq.x, xp, fmaf(bq.y, yp, bq.z));
        float w2a = 1.f - w0a - w1a;
        float zl = fmaf(c.x, xp, fmaf(c.y, yp, c.z));
        float wmin = fminf(fminf(w0a, w1a), w2a);
        if (wmin >= -a.w && zl <= zmin + bq.w) {
          int fi = __float_as_int(c.w);
          const float4* ep = fdE + (bOff + fi) * 3;
          float4 e0 = ep[0], e1 = ep[1], e2 = ep[2];
          float dx = __fsub_rn(xp, e0.x), dy = __fsub_rn(yp, e0.y);
          float num0 = __fadd_rn(__fmul_rn(e0.z, dx), __fmul_rn(e0.w, dy));
          float num1 = __fadd_rn(__fmul_rn(e1.x, dx), __fmul_rn(e1.y, dy));
          float w0 = __fdiv_rn(num0, e1.z);
          float w1 = __fdiv_rn(num1, e1.z);
          float w2 = __fsub_rn(__fsub_rn(1.f, w0), w1);
          if (w0 >= 0.f && w1 >= 0.f && w2 >= 0.f) {
            float z = __fadd_rn(
                __fadd_rn(__fmul_rn(w0, e1.w), __fmul_rn(w1, e2.x)),
                __fmul_rn(w2, e2.y));
            if (z < zmin || (z == zmin && fi < best)) {
              zmin = z; best = fi; bw0 = w0; bw1 = w1; bw2 = w2;
            }
          }
        }
      }
    }
  }

  if (!live) return;

  float rv, av;
  if (zmin < INFINITY) {
    int i0 = faces[3 * best + 0], i1 = faces[3 * best + 1], i2 = faces[3 * best + 2];
    const float* vb = verts + (size_t)b * kNV * 3;
    const float* nb = nrm + (size_t)b * kNV * 3;
    float px_ = bw0 * vb[3 * i0 + 0] + bw1 * vb[3 * i1 + 0] + bw2 * vb[3 * i2 + 0];
    float py_ = bw0 * vb[3 * i0 + 1] + bw1 * vb[3 * i1 + 1] + bw2 * vb[3 * i2 + 1];
    float pz_ = bw0 * vb[3 * i0 + 2] + bw1 * vb[3 * i1 + 2] + bw2 * vb[3 * i2 + 2];
    float nx = bw0 * nb[3 * i0 + 0] + bw1 * nb[3 * i1 + 0] + bw2 * nb[3 * i2 + 0];
    float ny = bw0 * nb[3 * i0 + 1] + bw1 * nb[3 * i1 + 1] + bw2 * nb[3 * i2 + 1];
    float nz = bw0 * nb[3 * i0 + 2] + bw1 * nb[3 * i1 + 2] + bw2 * nb[3 * i2 + 2];
    float nn = sqrtf(nx * nx + ny * ny + nz * nz);
    float nd = fmaxf(nn, kEps);
    nx /= nd; ny /= nd; nz /= nd;
    float pn = sqrtf(px_ * px_ + py_ * py_ + pz_ * pz_);
    float pd = fmaxf(pn, kEps);
    float lx = -px_ / pd, ly = -py_ / pd, lz = -pz_ / pd;
    float sdot = nx * lx + ny * ly + nz * lz;
    float ndl = fmaxf(sdot, 0.0f);
    float rx = 2.0f * sdot * nx - lx;
    float ry = 2.0f * sdot * ny - ly;
    float rz = 2.0f * sdot * nz - lz;
    float vdr = fmaxf(lx * rx + ly * ry + lz * rz, 0.0f);
    float qv = vdr;   // vdr^64 via 6 squarings
    qv = qv * qv; qv = qv * qv; qv = qv * qv;
    qv = qv * qv; qv = qv * qv; qv = qv * qv;
    float shade = 0.5f * (0.5f + 0.3f * ndl) + 0.2f * qv;
    rv = fminf(fmaxf(shade, 0.0f), 255.0f);
    av = 1.0f;
  } else {
    rv = 1.0f;
    av = 0.0f;
  }
  ((float4*)out)[((size_t)b * kH + y) * kW + x] = make_float4(rv, rv, rv, av);
}

}  // namespace

extern "C" void kernel_launch(void* const* d_in, const int* in_sizes, int n_in,
                              void* d_out, int out_size, void* d_ws, size_t ws_size,
                              hipStream_t stream) {
  (void)in_sizes; (void)n_in; (void)out_size; (void)ws_size;
  const float* verts = (const float*)d_in[0];   // (B, NV, 3) f32
  const int* faces = (const int*)d_in[1];       // (NF, 3) i32
  float* out = (float*)d_out;                   // (B, H, W, 4) f32
  float* ws = (float*)d_ws;

  // ws layout (float offsets; total ~6.46 MB, within proven ws >= 6.52 MB):
  //   nacc @ 0          (30,138)
  //   proj @ 30,720     (float4 x 10,046)
  //   fdE  @ 71,680     (float4 x 59,856)
  //   fdP  @ 311,296    (float4 x 59,856)
  //   fdB  @ 550,912    (float4 x 19,952)
  //   zr   @ 630,784    (u32 x 4)
  //   cnt  @ 630,912    (u32 x 16,384)
  //   off  @ 647,296    (u32 x 16,385)
  //   list @ 663,808    (u16 x 1,900,000)
  float* nacc = ws;
  float4* proj = (float4*)(ws + 30720);
  float4* fdE = (float4*)(ws + 71680);
  float4* fdP = (float4*)(ws + 311296);
  float4* fdB = (float4*)(ws + 550912);
  unsigned* zr = (unsigned*)(ws + 630784);
  unsigned* cnt = (unsigned*)(ws + 630912);
  unsigned* off = (unsigned*)(ws + 647296);
  unsigned short* list = (unsigned short*)(ws + 663808);

  hipLaunchKernelGGL(init_k, dim3(120), dim3(256), 0, stream, nacc, cnt, zr);
  hipLaunchKernelGGL(normal_accum_k, dim3((kB * kNF + 255) / 256), dim3(256), 0,
                     stream, verts, faces, nacc);
  hipLaunchKernelGGL(proj_norm_k, dim3((kB * kNV + 255) / 256), dim3(256), 0,
                     stream, verts, nacc, proj);
  hipLaunchKernelGGL(face_setup_k, dim3((kB * kNF + 255) / 256), dim3(256), 0,
                     stream, proj, faces, fdE, fdP, fdB, zr);
  hipLaunchKernelGGL((bin_k<false>), dim3((kNF + 255) / 256, 32, kB), dim3(256),
                     0, stream, fdP, fdB, zr, cnt, list);
  hipLaunchKernelGGL(scan_k, dim3(1), dim3(256), 0, stream, cnt, off);
  hipLaunchKernelGGL((bin_k<true>), dim3((kNF + 255) / 256, 32, kB), dim3(256),
                     0, stream, fdP, fdB, zr, cnt, list);
  hipLaunchKernelGGL(raster_k, dim3(32, 32, kB), dim3(256), 0, stream,
                     fdP, fdE, off, list, zr, verts, nacc, faces, out);
}

// Round 5
// 349.315 us; speedup vs baseline: 2.2667x; 2.2667x over previous
//
#include <hip/hip_runtime.h>
#include <math.h>

namespace {

constexpr int kH = 500, kW = 500, kNV = 5023, kNF = 9976, kB = 2;
constexpr float kFocal = 1015.0f;
constexpr float kEps = 1e-6f;
constexpr int kNB = 8;                       // z buckets per tile
constexpr unsigned kListCap = 1900000u;      // u16 entries (expected ~860k)

// ---------------------------------------------------------------- utilities
__device__ inline void cross3(float ax, float ay, float az,
                              float bx, float by, float bz,
                              float& cx, float& cy, float& cz) {
  cx = ay * bz - az * by;
  cy = az * bx - ax * bz;
  cz = ax * by - ay * bx;
}

// Edge-separation triangle-vs-tile cull. MUST be bit-identical between count
// and fill passes (shared fn, same inputs -> deterministic counts).
__device__ inline bool tileCull(const float4 r0, const float4 r1,
                                float tX0, float tX1, float tY0, float tY1) {
  float hi0 = fmaf(r0.x, r0.x >= 0.f ? tX1 : tX0,
                   fmaf(r0.y, r0.y >= 0.f ? tY1 : tY0, r0.z));
  float lo0 = fmaf(r0.x, r0.x >= 0.f ? tX0 : tX1,
                   fmaf(r0.y, r0.y >= 0.f ? tY0 : tY1, r0.z));
  float hi1 = fmaf(r1.x, r1.x >= 0.f ? tX1 : tX0,
                   fmaf(r1.y, r1.y >= 0.f ? tY1 : tY0, r1.z));
  float lo1 = fmaf(r1.x, r1.x >= 0.f ? tX0 : tX1,
                   fmaf(r1.y, r1.y >= 0.f ? tY0 : tY1, r1.z));
  float m2 = 2.f * r0.w;   // looser than the per-pixel margin -mw: conservative
  return hi0 >= -m2 && hi1 >= -m2 && (1.f - lo0 - lo1) >= -m2;
}

__device__ inline int bucketOf(float zminf, float zlo, float iscale) {
  float t = (zminf - zlo) * iscale;
  t = fminf(fmaxf(t, 0.f), (float)(kNB - 1));   // fmaxf(nan,0)=0 -> safe
  return (int)t;
}

// ---------------------------------------------------------------- kernels
__global__ void init_k(float* nacc, unsigned* cnt, unsigned* zr) {
  int i = blockIdx.x * 256 + threadIdx.x;
  if (i < kB * kNV * 3) nacc[i] = 0.0f;
  if (i < kB * 32 * 32 * kNB) cnt[i] = 0u;
  if (i < 2 * kB) zr[i] = (i & 1) ? 0u : 0x7F800000u;  // {min=+inf, max=0} bits
}

__global__ void normal_accum_k(const float* __restrict__ verts,
                               const int* __restrict__ faces,
                               float* __restrict__ nacc) {
  int idx = blockIdx.x * 256 + threadIdx.x;
  if (idx >= kB * kNF) return;
  int b = idx / kNF, f = idx - b * kNF;
  int i0 = faces[3 * f + 0], i1 = faces[3 * f + 1], i2 = faces[3 * f + 2];
  const float* vb = verts + (size_t)b * kNV * 3;
  float x0 = vb[3 * i0], y0 = vb[3 * i0 + 1], z0 = vb[3 * i0 + 2];
  float x1 = vb[3 * i1], y1 = vb[3 * i1 + 1], z1 = vb[3 * i1 + 2];
  float x2 = vb[3 * i2], y2 = vb[3 * i2 + 1], z2 = vb[3 * i2 + 2];
  float* nb = nacc + (size_t)b * kNV * 3;
  float cx, cy, cz;
  cross3(x2 - x1, y2 - y1, z2 - z1, x0 - x1, y0 - y1, z0 - z1, cx, cy, cz);
  atomicAdd(nb + 3 * i1 + 0, cx);
  atomicAdd(nb + 3 * i1 + 1, cy);
  atomicAdd(nb + 3 * i1 + 2, cz);
  cross3(x0 - x2, y0 - y2, z0 - z2, x1 - x2, y1 - y2, z1 - z2, cx, cy, cz);
  atomicAdd(nb + 3 * i2 + 0, cx);
  atomicAdd(nb + 3 * i2 + 1, cy);
  atomicAdd(nb + 3 * i2 + 2, cz);
  cross3(x1 - x0, y1 - y0, z1 - z0, x2 - x0, y2 - y0, z2 - z0, cx, cy, cz);
  atomicAdd(nb + 3 * i0 + 0, cx);
  atomicAdd(nb + 3 * i0 + 1, cy);
  atomicAdd(nb + 3 * i0 + 2, cz);
}

__global__ void proj_norm_k(const float* __restrict__ verts,
                            float* __restrict__ nacc,
                            float4* __restrict__ proj) {
  int idx = blockIdx.x * 256 + threadIdx.x;
  if (idx >= kB * kNV) return;
  float nx = nacc[3 * idx + 0], ny = nacc[3 * idx + 1], nz = nacc[3 * idx + 2];
  float nn = sqrtf(nx * nx + ny * ny + nz * nz);
  float nd = fmaxf(nn, kEps);
  nacc[3 * idx + 0] = nx / nd;
  nacc[3 * idx + 1] = ny / nd;
  nacc[3 * idx + 2] = nz / nd;
  float vx = verts[3 * idx + 0], vy = verts[3 * idx + 1], vz = verts[3 * idx + 2];
  float xc = -vx, yc = vy, zc = -vz;
  float zs = fmaxf(zc, kEps);
  float px = __fsub_rn(0.5f * kW, __fdiv_rn(__fmul_rn(kFocal, xc), zs));
  float py = __fsub_rn(0.5f * kH, __fdiv_rn(__fmul_rn(kFocal, yc), zs));
  proj[idx] = make_float4(px, py, zc, 0.0f);
}

// fdE (3 float4): {cx,cy,A0,B0} {A1,B1,den,za} {zb,zc,0,0}   (exact path)
// fdP (3 float4): {P0,Q0,R0,mw} {P1,Q1,R1,mz} {Zx,Zy,Zc,zminf} (prefilter)
// fdB (1 float4): bbox {minx,maxx,miny,maxy}, inf-sentinel if invalid
// Grid: (ceil(kNF/256), kB) so every wave is batch-uniform; z-range reduced
// per-wave via __shfl_xor butterfly -> ONE atomic per wave (~320 total, vs
// 20k same-address atomics that serialized at ~55cyc each = 455us in R3).
__global__ void face_setup_k(const float4* __restrict__ proj,
                             const int* __restrict__ faces,
                             float4* __restrict__ fdE,
                             float4* __restrict__ fdP,
                             float4* __restrict__ fdB,
                             unsigned* __restrict__ zr) {
  int f = blockIdx.x * 256 + threadIdx.x;
  int b = blockIdx.y;
  bool act = (f < kNF);
  float redMin = INFINITY, redMax = 0.0f;   // neutral for inactive/invalid
  if (act) {
    size_t idx = (size_t)b * kNF + f;
    int i0 = faces[3 * f + 0], i1 = faces[3 * f + 1], i2 = faces[3 * f + 2];
    float4 A = proj[b * kNV + i0];
    float4 Bv = proj[b * kNV + i1];
    float4 C = proj[b * kNV + i2];
    float ax = A.x, ay = A.y, za = A.z;
    float bx = Bv.x, by = Bv.y, zb = Bv.z;
    float cx = C.x, cy = C.y, zc = C.z;
    float A0 = __fsub_rn(by, cy);
    float B0 = __fsub_rn(cx, bx);
    float A1 = __fsub_rn(cy, ay);
    float B1 = __fsub_rn(ax, cx);
    float e = __fsub_rn(ay, cy);
    float den = __fadd_rn(__fmul_rn(A0, B1), __fmul_rn(B0, e));
    bool valid =
        (fabsf(den) >= kEps) && (za > kEps) && (zb > kEps) && (zc > kEps);
    float ds = valid ? den : 1.0f;

    float4* oe = fdE + idx * 3;
    oe[0] = make_float4(cx, cy, A0, B0);
    oe[1] = make_float4(A1, B1, ds, za);
    oe[2] = make_float4(zb, zc, 0.0f, 0.0f);

    float P0 = A0 / ds, Q0 = B0 / ds, R0 = -(A0 * cx + B0 * cy) / ds;
    float P1 = A1 / ds, Q1 = B1 / ds, R1 = -(A1 * cx + B1 * cy) / ds;
    float dza = za - zc, dzb = zb - zc;
    float Zx = dza * P0 + dzb * P1;
    float Zy = dza * Q0 + dzb * Q1;
    float Zc = dza * R0 + dzb * R1 + zc;
    float S0 = (fabsf(P0) + fabsf(Q0)) * 512.f + fabsf(R0);
    float S1 = (fabsf(P1) + fabsf(Q1)) * 512.f + fabsf(R1);
    float Sz = (fabsf(Zx) + fabsf(Zy)) * 512.f + fabsf(Zc);
    float m0 = S0 * 0x1p-18f;
    float m1 = S1 * 0x1p-18f;
    float mw = m0 + m1 + 2e-6f;
    float mz = m0 * fabsf(dza) + m1 * fabsf(dzb) + Sz * 0x1p-18f +
               0x1p-18f * (fabsf(zc) + fabsf(dza) + fabsf(dzb) + 1.f) + 2e-6f;
    float zminf = fminf(fminf(za, zb), zc);

    float4* op = fdP + idx * 3;
    op[0] = make_float4(P0, Q0, R0, mw);
    op[1] = make_float4(P1, Q1, R1, mz);
    op[2] = make_float4(Zx, Zy, Zc, zminf);

    float mnx, mxx, mny, mxy;
    if (valid) {
      mnx = fminf(fminf(ax, bx), cx) - 0.5f;
      mxx = fmaxf(fmaxf(ax, bx), cx) + 0.5f;
      mny = fminf(fminf(ay, by), cy) - 0.5f;
      mxy = fmaxf(fmaxf(ay, by), cy) + 0.5f;
      redMin = zminf;   // zminf > eps > 0 -> uint bit-order == float order
      redMax = zminf;
    } else {
      mnx = INFINITY; mxx = -INFINITY; mny = INFINITY; mxy = -INFINITY;
    }
    fdB[idx] = make_float4(mnx, mxx, mny, mxy);
  }
  // Wave-level butterfly (all 64 lanes alive; wave is batch-uniform).
#pragma unroll
  for (int d = 32; d >= 1; d >>= 1) {
    redMin = fminf(redMin, __shfl_xor(redMin, d, 64));
    redMax = fmaxf(redMax, __shfl_xor(redMax, d, 64));
  }
  if ((threadIdx.x & 63) == 0 && redMin < INFINITY) {
    atomicMin(zr + 2 * b + 0, __float_as_uint(redMin));
    atomicMax(zr + 2 * b + 1, __float_as_uint(redMax));
  }
}

// Binning: thread = (face, tile-row, batch). Walks the bbox's tile columns,
// culls, and counts (FILL=0) or appends u16 face idx (FILL=1). cnt doubles as
// the fill cursor (scan pre-sets it to the exclusive offsets).
template <bool FILL>
__global__ void bin_k(const float4* __restrict__ fdP,
                      const float4* __restrict__ fdB,
                      const unsigned* __restrict__ zr,
                      unsigned* __restrict__ cnt,
                      unsigned short* __restrict__ list) {
  int f = blockIdx.x * 256 + threadIdx.x;
  if (f >= kNF) return;
  int b = blockIdx.z, ty = blockIdx.y;
  size_t bOff = (size_t)b * kNF;
  float4 bb = fdB[bOff + f];
  float tY0 = 16.f * ty + 0.5f, tY1 = tY0 + 15.f;
  if (!(bb.z <= tY1 && bb.w >= tY0)) return;
  // Tile-column range covered by bbox (clamped in float to avoid huge-cvt UB).
  float t0f = fminf(fmaxf(ceilf((bb.x - 15.5f) * 0.0625f), 0.f), 31.f);
  float t1f = fminf(fmaxf(floorf((bb.y - 0.5f) * 0.0625f), 0.f), 31.f);
  int tx0 = (int)t0f, tx1 = (int)t1f;
  if (tx0 > tx1) return;
  const float4* rp = fdP + (bOff + f) * 3;
  float4 r0 = rp[0], r1 = rp[1], r2 = rp[2];
  float zlo = __uint_as_float(zr[2 * b]);
  float zhi = __uint_as_float(zr[2 * b + 1]);
  float range = zhi - zlo;
  float iscale = range > 1e-30f ? (float)kNB / range : 0.f;
  int q = bucketOf(r2.w, zlo, iscale);
  for (int tx = tx0; tx <= tx1; ++tx) {
    float tX0 = 16.f * tx + 0.5f, tX1 = tX0 + 15.f;
    if (tileCull(r0, r1, tX0, tX1, tY0, tY1)) {
      unsigned i = (unsigned)((b * 32 + ty) * 32 + tx) * kNB + q;
      if (FILL) {
        unsigned pos = atomicAdd(&cnt[i], 1u);
        if (pos < kListCap) list[pos] = (unsigned short)f;
      } else {
        atomicAdd(&cnt[i], 1u);
      }
    }
  }
}

// Exclusive scan over the 16384 (tile,bucket) counts. Single 256-thread block;
// writes off[] (for raster) and resets cnt[] to the offsets (fill cursors).
__global__ void scan_k(unsigned* __restrict__ cnt, unsigned* __restrict__ off) {
  constexpr int N = kB * 32 * 32 * kNB;   // 16384
  constexpr int PER = N / 256;            // 64
  __shared__ unsigned part[256];
  __shared__ unsigned base[256];
  __shared__ unsigned total;
  int t = threadIdx.x;
  unsigned loc[PER];
  unsigned s = 0;
#pragma unroll
  for (int i = 0; i < PER; ++i) { loc[i] = cnt[t * PER + i]; s += loc[i]; }
  part[t] = s;
  __syncthreads();
  if (t == 0) {
    unsigned r = 0;
    for (int i = 0; i < 256; ++i) { base[i] = r; r += part[i]; }
    total = r;
  }
  __syncthreads();
  unsigned r = base[t];
#pragma unroll
  for (int i = 0; i < PER; ++i) {
    off[t * PER + i] = r;
    cnt[t * PER + i] = r;
    r += loc[i];
  }
  if (t == 0) off[N] = total;
}

// 16x16-pixel tile per block; iterates its pre-binned candidate list bucket by
// bucket (front-to-back), LDS-staging 256 candidates at a time. Early-break
// when ALL pixels' zmin beats the conservative lower bound of later buckets
// (strictly safe: skipped candidates have exact z > zmin, ties impossible).
// Discrete decisions replicate reference fp32 rounding; (z,idx) lex-min is
// order-independent == jnp.argmin first-min. Shading fused.
__global__ __launch_bounds__(256) void raster_k(
    const float4* __restrict__ fdP, const float4* __restrict__ fdE,
    const unsigned* __restrict__ off, const unsigned short* __restrict__ list,
    const unsigned* __restrict__ zr, const float* __restrict__ verts,
    const float* __restrict__ nrm, const int* __restrict__ faces,
    float* __restrict__ out) {
  __shared__ float4 sA[256], sB[256], sC[256];   // 12 KiB
  int b = blockIdx.z;
  size_t bOff = (size_t)b * kNF;
  int tx = threadIdx.x & 15, ty = threadIdx.x >> 4;
  int x = blockIdx.x * 16 + tx;
  int y = blockIdx.y * 16 + ty;
  float xp = (float)x + 0.5f;
  float yp = (float)y + 0.5f;
  bool live = (x < kW && y < kH);
  float zmin = live ? INFINITY : -INFINITY;   // dead px never block the break
  int best = 0x7FFFFFFF;
  float bw0 = 0.f, bw1 = 0.f, bw2 = 0.f;

  float zlo = __uint_as_float(zr[2 * b]);
  float zhi = __uint_as_float(zr[2 * b + 1]);
  float range = zhi - zlo;
  float bwid = range > 1e-30f ? range * (1.f / kNB) : 0.f;
  const unsigned* offT =
      off + (unsigned)((b * 32 + blockIdx.y) * 32 + blockIdx.x) * kNB;

  for (int q = 0; q < kNB; ++q) {
    if (q > 0) {
      float lb = zlo + (float)q * bwid * (1.f - 1e-5f) - 2e-5f;
      if (__syncthreads_and(zmin < lb)) break;
    }
    unsigned s = offT[q], e = offT[q + 1];
    for (unsigned base = s; base < e; base += 256) {
      int n = min(256u, e - base);
      __syncthreads();
      if ((int)threadIdx.x < n) {
        unsigned fi = list[base + threadIdx.x];
        const float4* rp = fdP + (bOff + fi) * 3;
        float4 r0 = rp[0], r1 = rp[1], r2 = rp[2];
        r2.w = __int_as_float((int)fi);
        sA[threadIdx.x] = r0;
        sB[threadIdx.x] = r1;
        sC[threadIdx.x] = r2;
      }
      __syncthreads();
      for (int k = 0; k < n; ++k) {
        float4 a = sA[k], bq = sB[k], c = sC[k];
        float w0a = fmaf(a.x, xp, fmaf(a.y, yp, a.z));
        float w1a = fmaf(bq.x, xp, fmaf(bq.y, yp, bq.z));
        float w2a = 1.f - w0a - w1a;
        float zl = fmaf(c.x, xp, fmaf(c.y, yp, c.z));
        float wmin = fminf(fminf(w0a, w1a), w2a);
        if (wmin >= -a.w && zl <= zmin + bq.w) {
          int fi = __float_as_int(c.w);
          const float4* ep = fdE + (bOff + fi) * 3;
          float4 e0 = ep[0], e1 = ep[1], e2 = ep[2];
          float dx = __fsub_rn(xp, e0.x), dy = __fsub_rn(yp, e0.y);
          float num0 = __fadd_rn(__fmul_rn(e0.z, dx), __fmul_rn(e0.w, dy));
          float num1 = __fadd_rn(__fmul_rn(e1.x, dx), __fmul_rn(e1.y, dy));
          float w0 = __fdiv_rn(num0, e1.z);
          float w1 = __fdiv_rn(num1, e1.z);
          float w2 = __fsub_rn(__fsub_rn(1.f, w0), w1);
          if (w0 >= 0.f && w1 >= 0.f && w2 >= 0.f) {
            float z = __fadd_rn(
                __fadd_rn(__fmul_rn(w0, e1.w), __fmul_rn(w1, e2.x)),
                __fmul_rn(w2, e2.y));
            if (z < zmin || (z == zmin && fi < best)) {
              zmin = z; best = fi; bw0 = w0; bw1 = w1; bw2 = w2;
            }
          }
        }
      }
    }
  }

  if (!live) return;

  float rv, av;
  if (zmin < INFINITY) {
    int i0 = faces[3 * best + 0], i1 = faces[3 * best + 1], i2 = faces[3 * best + 2];
    const float* vb = verts + (size_t)b * kNV * 3;
    const float* nb = nrm + (size_t)b * kNV * 3;
    float px_ = bw0 * vb[3 * i0 + 0] + bw1 * vb[3 * i1 + 0] + bw2 * vb[3 * i2 + 0];
    float py_ = bw0 * vb[3 * i0 + 1] + bw1 * vb[3 * i1 + 1] + bw2 * vb[3 * i2 + 1];
    float pz_ = bw0 * vb[3 * i0 + 2] + bw1 * vb[3 * i1 + 2] + bw2 * vb[3 * i2 + 2];
    float nx = bw0 * nb[3 * i0 + 0] + bw1 * nb[3 * i1 + 0] + bw2 * nb[3 * i2 + 0];
    float ny = bw0 * nb[3 * i0 + 1] + bw1 * nb[3 * i1 + 1] + bw2 * nb[3 * i2 + 1];
    float nz = bw0 * nb[3 * i0 + 2] + bw1 * nb[3 * i1 + 2] + bw2 * nb[3 * i2 + 2];
    float nn = sqrtf(nx * nx + ny * ny + nz * nz);
    float nd = fmaxf(nn, kEps);
    nx /= nd; ny /= nd; nz /= nd;
    float pn = sqrtf(px_ * px_ + py_ * py_ + pz_ * pz_);
    float pd = fmaxf(pn, kEps);
    float lx = -px_ / pd, ly = -py_ / pd, lz = -pz_ / pd;
    float sdot = nx * lx + ny * ly + nz * lz;
    float ndl = fmaxf(sdot, 0.0f);
    float rx = 2.0f * sdot * nx - lx;
    float ry = 2.0f * sdot * ny - ly;
    float rz = 2.0f * sdot * nz - lz;
    float vdr = fmaxf(lx * rx + ly * ry + lz * rz, 0.0f);
    float qv = vdr;   // vdr^64 via 6 squarings
    qv = qv * qv; qv = qv * qv; qv = qv * qv;
    qv = qv * qv; qv = qv * qv; qv = qv * qv;
    float shade = 0.5f * (0.5f + 0.3f * ndl) + 0.2f * qv;
    rv = fminf(fmaxf(shade, 0.0f), 255.0f);
    av = 1.0f;
  } else {
    rv = 1.0f;
    av = 0.0f;
  }
  ((float4*)out)[((size_t)b * kH + y) * kW + x] = make_float4(rv, rv, rv, av);
}

}  // namespace

extern "C" void kernel_launch(void* const* d_in, const int* in_sizes, int n_in,
                              void* d_out, int out_size, void* d_ws, size_t ws_size,
                              hipStream_t stream) {
  (void)in_sizes; (void)n_in; (void)out_size; (void)ws_size;
  const float* verts = (const float*)d_in[0];   // (B, NV, 3) f32
  const int* faces = (const int*)d_in[1];       // (NF, 3) i32
  float* out = (float*)d_out;                   // (B, H, W, 4) f32
  float* ws = (float*)d_ws;

  // ws layout (float offsets; total ~6.46 MB, within proven ws >= 6.52 MB):
  //   nacc @ 0          (30,138)
  //   proj @ 30,720     (float4 x 10,046)
  //   fdE  @ 71,680     (float4 x 59,856)
  //   fdP  @ 311,296    (float4 x 59,856)
  //   fdB  @ 550,912    (float4 x 19,952)
  //   zr   @ 630,784    (u32 x 4)
  //   cnt  @ 630,912    (u32 x 16,384)
  //   off  @ 647,296    (u32 x 16,385)
  //   list @ 663,808    (u16 x 1,900,000)
  float* nacc = ws;
  float4* proj = (float4*)(ws + 30720);
  float4* fdE = (float4*)(ws + 71680);
  float4* fdP = (float4*)(ws + 311296);
  float4* fdB = (float4*)(ws + 550912);
  unsigned* zr = (unsigned*)(ws + 630784);
  unsigned* cnt = (unsigned*)(ws + 630912);
  unsigned* off = (unsigned*)(ws + 647296);
  unsigned short* list = (unsigned short*)(ws + 663808);

  hipLaunchKernelGGL(init_k, dim3(120), dim3(256), 0, stream, nacc, cnt, zr);
  hipLaunchKernelGGL(normal_accum_k, dim3((kB * kNF + 255) / 256), dim3(256), 0,
                     stream, verts, faces, nacc);
  hipLaunchKernelGGL(proj_norm_k, dim3((kB * kNV + 255) / 256), dim3(256), 0,
                     stream, verts, nacc, proj);
  hipLaunchKernelGGL(face_setup_k, dim3((kNF + 255) / 256, kB), dim3(256), 0,
                     stream, proj, faces, fdE, fdP, fdB, zr);
  hipLaunchKernelGGL((bin_k<false>), dim3((kNF + 255) / 256, 32, kB), dim3(256),
                     0, stream, fdP, fdB, zr, cnt, list);
  hipLaunchKernelGGL(scan_k, dim3(1), dim3(256), 0, stream, cnt, off);
  hipLaunchKernelGGL((bin_k<true>), dim3((kNF + 255) / 256, 32, kB), dim3(256),
                     0, stream, fdP, fdB, zr, cnt, list);
  hipLaunchKernelGGL(raster_k, dim3(32, 32, kB), dim3(256), 0, stream,
                     fdP, fdE, off, list, zr, verts, nacc, faces, out);
}

// Round 6
// 206.203 us; speedup vs baseline: 3.8398x; 1.6940x over previous
//
#include <hip/hip_runtime.h>
#include <math.h>

namespace {

constexpr int kH = 500, kW = 500, kNV = 5023, kNF = 9976, kB = 2;
constexpr float kFocal = 1015.0f;
constexpr float kEps = 1e-6f;
constexpr int kNB = 8;                       // z buckets per tile
constexpr int kChunks = 4;                   // face chunks (binning blocks)
constexpr int kFPC = (kNF + kChunks - 1) / kChunks;   // 2494 faces/chunk
constexpr int kNBins = kB * 32 * 32 * kNB * kChunks;  // 65536 (bin,chunk) cells
constexpr unsigned kListCap = 1830000u;      // u16 entries (expected ~860k)

// ---------------------------------------------------------------- utilities
__device__ inline void cross3(float ax, float ay, float az,
                              float bx, float by, float bz,
                              float& cx, float& cy, float& cz) {
  cx = ay * bz - az * by;
  cy = az * bx - ax * bz;
  cz = ax * by - ay * bx;
}

// Edge-separation triangle-vs-tile cull. MUST be bit-identical between count
// and fill passes (shared fn, same inputs -> deterministic counts).
__device__ inline bool tileCull(const float4 r0, const float4 r1,
                                float tX0, float tX1, float tY0, float tY1) {
  float hi0 = fmaf(r0.x, r0.x >= 0.f ? tX1 : tX0,
                   fmaf(r0.y, r0.y >= 0.f ? tY1 : tY0, r0.z));
  float lo0 = fmaf(r0.x, r0.x >= 0.f ? tX0 : tX1,
                   fmaf(r0.y, r0.y >= 0.f ? tY0 : tY1, r0.z));
  float hi1 = fmaf(r1.x, r1.x >= 0.f ? tX1 : tX0,
                   fmaf(r1.y, r1.y >= 0.f ? tY1 : tY0, r1.z));
  float lo1 = fmaf(r1.x, r1.x >= 0.f ? tX0 : tX1,
                   fmaf(r1.y, r1.y >= 0.f ? tY0 : tY1, r1.z));
  float m2 = 2.f * r0.w;   // looser than the per-pixel margin -mw: conservative
  return hi0 >= -m2 && hi1 >= -m2 && (1.f - lo0 - lo1) >= -m2;
}

__device__ inline int bucketOf(float zminf, float zlo, float iscale) {
  float t = (zminf - zlo) * iscale;
  t = fminf(fmaxf(t, 0.f), (float)(kNB - 1));   // fmaxf(nan,0)=0 -> safe
  return (int)t;
}

// ---------------------------------------------------------------- kernels
__global__ void init_k(float* nacc, unsigned* zr) {
  int i = blockIdx.x * 256 + threadIdx.x;
  if (i < kB * kNV * 3) nacc[i] = 0.0f;
  if (i < 2 * kB) zr[i] = (i & 1) ? 0u : 0x7F800000u;  // {min=+inf, max=0} bits
}

__global__ void normal_accum_k(const float* __restrict__ verts,
                               const int* __restrict__ faces,
                               float* __restrict__ nacc) {
  int idx = blockIdx.x * 256 + threadIdx.x;
  if (idx >= kB * kNF) return;
  int b = idx / kNF, f = idx - b * kNF;
  int i0 = faces[3 * f + 0], i1 = faces[3 * f + 1], i2 = faces[3 * f + 2];
  const float* vb = verts + (size_t)b * kNV * 3;
  float x0 = vb[3 * i0], y0 = vb[3 * i0 + 1], z0 = vb[3 * i0 + 2];
  float x1 = vb[3 * i1], y1 = vb[3 * i1 + 1], z1 = vb[3 * i1 + 2];
  float x2 = vb[3 * i2], y2 = vb[3 * i2 + 1], z2 = vb[3 * i2 + 2];
  float* nb = nacc + (size_t)b * kNV * 3;
  float cx, cy, cz;
  cross3(x2 - x1, y2 - y1, z2 - z1, x0 - x1, y0 - y1, z0 - z1, cx, cy, cz);
  atomicAdd(nb + 3 * i1 + 0, cx);
  atomicAdd(nb + 3 * i1 + 1, cy);
  atomicAdd(nb + 3 * i1 + 2, cz);
  cross3(x0 - x2, y0 - y2, z0 - z2, x1 - x2, y1 - y2, z1 - z2, cx, cy, cz);
  atomicAdd(nb + 3 * i2 + 0, cx);
  atomicAdd(nb + 3 * i2 + 1, cy);
  atomicAdd(nb + 3 * i2 + 2, cz);
  cross3(x1 - x0, y1 - y0, z1 - z0, x2 - x0, y2 - y0, z2 - z0, cx, cy, cz);
  atomicAdd(nb + 3 * i0 + 0, cx);
  atomicAdd(nb + 3 * i0 + 1, cy);
  atomicAdd(nb + 3 * i0 + 2, cz);
}

__global__ void proj_norm_k(const float* __restrict__ verts,
                            float* __restrict__ nacc,
                            float4* __restrict__ proj) {
  int idx = blockIdx.x * 256 + threadIdx.x;
  if (idx >= kB * kNV) return;
  float nx = nacc[3 * idx + 0], ny = nacc[3 * idx + 1], nz = nacc[3 * idx + 2];
  float nn = sqrtf(nx * nx + ny * ny + nz * nz);
  float nd = fmaxf(nn, kEps);
  nacc[3 * idx + 0] = nx / nd;
  nacc[3 * idx + 1] = ny / nd;
  nacc[3 * idx + 2] = nz / nd;
  float vx = verts[3 * idx + 0], vy = verts[3 * idx + 1], vz = verts[3 * idx + 2];
  float xc = -vx, yc = vy, zc = -vz;
  float zs = fmaxf(zc, kEps);
  float px = __fsub_rn(0.5f * kW, __fdiv_rn(__fmul_rn(kFocal, xc), zs));
  float py = __fsub_rn(0.5f * kH, __fdiv_rn(__fmul_rn(kFocal, yc), zs));
  proj[idx] = make_float4(px, py, zc, 0.0f);
}

// fdE (3 float4): {cx,cy,A0,B0} {A1,B1,den,za} {zb,zc,0,0}   (exact path)
// fdP (3 float4): {P0,Q0,R0,mw} {P1,Q1,R1,mz} {Zx,Zy,Zc,zminf} (prefilter)
// fdB (1 float4): bbox {minx,maxx,miny,maxy}, inf-sentinel if invalid
// Wave-level z-range butterfly -> one atomic per wave (R3 lesson: 20k
// same-address global atomics serialized into 455us).
__global__ void face_setup_k(const float4* __restrict__ proj,
                             const int* __restrict__ faces,
                             float4* __restrict__ fdE,
                             float4* __restrict__ fdP,
                             float4* __restrict__ fdB,
                             unsigned* __restrict__ zr) {
  int f = blockIdx.x * 256 + threadIdx.x;
  int b = blockIdx.y;
  bool act = (f < kNF);
  float redMin = INFINITY, redMax = 0.0f;   // neutral for inactive/invalid
  if (act) {
    size_t idx = (size_t)b * kNF + f;
    int i0 = faces[3 * f + 0], i1 = faces[3 * f + 1], i2 = faces[3 * f + 2];
    float4 A = proj[b * kNV + i0];
    float4 Bv = proj[b * kNV + i1];
    float4 C = proj[b * kNV + i2];
    float ax = A.x, ay = A.y, za = A.z;
    float bx = Bv.x, by = Bv.y, zb = Bv.z;
    float cx = C.x, cy = C.y, zc = C.z;
    float A0 = __fsub_rn(by, cy);
    float B0 = __fsub_rn(cx, bx);
    float A1 = __fsub_rn(cy, ay);
    float B1 = __fsub_rn(ax, cx);
    float e = __fsub_rn(ay, cy);
    float den = __fadd_rn(__fmul_rn(A0, B1), __fmul_rn(B0, e));
    bool valid =
        (fabsf(den) >= kEps) && (za > kEps) && (zb > kEps) && (zc > kEps);
    float ds = valid ? den : 1.0f;

    float4* oe = fdE + idx * 3;
    oe[0] = make_float4(cx, cy, A0, B0);
    oe[1] = make_float4(A1, B1, ds, za);
    oe[2] = make_float4(zb, zc, 0.0f, 0.0f);

    float P0 = A0 / ds, Q0 = B0 / ds, R0 = -(A0 * cx + B0 * cy) / ds;
    float P1 = A1 / ds, Q1 = B1 / ds, R1 = -(A1 * cx + B1 * cy) / ds;
    float dza = za - zc, dzb = zb - zc;
    float Zx = dza * P0 + dzb * P1;
    float Zy = dza * Q0 + dzb * Q1;
    float Zc = dza * R0 + dzb * R1 + zc;
    float S0 = (fabsf(P0) + fabsf(Q0)) * 512.f + fabsf(R0);
    float S1 = (fabsf(P1) + fabsf(Q1)) * 512.f + fabsf(R1);
    float Sz = (fabsf(Zx) + fabsf(Zy)) * 512.f + fabsf(Zc);
    float m0 = S0 * 0x1p-18f;
    float m1 = S1 * 0x1p-18f;
    float mw = m0 + m1 + 2e-6f;
    float mz = m0 * fabsf(dza) + m1 * fabsf(dzb) + Sz * 0x1p-18f +
               0x1p-18f * (fabsf(zc) + fabsf(dza) + fabsf(dzb) + 1.f) + 2e-6f;
    float zminf = fminf(fminf(za, zb), zc);

    float4* op = fdP + idx * 3;
    op[0] = make_float4(P0, Q0, R0, mw);
    op[1] = make_float4(P1, Q1, R1, mz);
    op[2] = make_float4(Zx, Zy, Zc, zminf);

    float mnx, mxx, mny, mxy;
    if (valid) {
      mnx = fminf(fminf(ax, bx), cx) - 0.5f;
      mxx = fmaxf(fmaxf(ax, bx), cx) + 0.5f;
      mny = fminf(fminf(ay, by), cy) - 0.5f;
      mxy = fmaxf(fmaxf(ay, by), cy) + 0.5f;
      redMin = zminf;   // zminf > eps > 0 -> uint bit-order == float order
      redMax = zminf;
    } else {
      mnx = INFINITY; mxx = -INFINITY; mny = INFINITY; mxy = -INFINITY;
    }
    fdB[idx] = make_float4(mnx, mxx, mny, mxy);
  }
#pragma unroll
  for (int d = 32; d >= 1; d >>= 1) {
    redMin = fminf(redMin, __shfl_xor(redMin, d, 64));
    redMax = fmaxf(redMax, __shfl_xor(redMax, d, 64));
  }
  if ((threadIdx.x & 63) == 0 && redMin < INFINITY) {
    atomicMin(zr + 2 * b + 0, __float_as_uint(redMin));
    atomicMax(zr + 2 * b + 1, __float_as_uint(redMax));
  }
}

// Block-local LDS binning. Block = (face-chunk c, tile-row ty, batch b);
// 256 LDS counters = 32 tile-cols x 8 z-buckets. COUNT: LDS atomics, then
// plain-store the 256 counts to cnt[(bin)*kChunks + c] (each cell written by
// exactly one block -> no global atomics, no pre-zeroing). FILL: seed LDS
// cursors from the scanned offsets, identical cull -> identical counts ->
// no overflow; plain u16 stores. (R4 lesson: 860k scattered global atomics
// = 22.8MB of line-flush HBM writes = 114us; LDS atomics are free.)
template <bool FILL>
__global__ __launch_bounds__(256) void bin_k(
    const float4* __restrict__ fdP, const float4* __restrict__ fdB,
    const unsigned* __restrict__ zr, unsigned* __restrict__ cnt,
    unsigned short* __restrict__ list) {
  __shared__ unsigned lc[256];
  int c = blockIdx.x, ty = blockIdx.y, b = blockIdx.z;
  size_t bOff = (size_t)b * kNF;
  int t = threadIdx.x;
  // Global cell index for this block's LDS slot t=(tx*8+q):
  unsigned gcell = (((unsigned)(b * 32 + ty) * 32) * kNB + (unsigned)t) *
                       kChunks + (unsigned)c;
  lc[t] = FILL ? cnt[gcell] : 0u;
  __syncthreads();

  float tY0 = 16.f * ty + 0.5f, tY1 = tY0 + 15.f;
  float zlo = __uint_as_float(zr[2 * b]);
  float zhi = __uint_as_float(zr[2 * b + 1]);
  float range = zhi - zlo;
  float iscale = range > 1e-30f ? (float)kNB / range : 0.f;
  int f0 = c * kFPC, f1 = min(kNF, f0 + kFPC);
  for (int f = f0 + t; f < f1; f += 256) {
    float4 bb = fdB[bOff + f];
    if (!(bb.z <= tY1 && bb.w >= tY0)) continue;
    float t0f = fminf(fmaxf(ceilf((bb.x - 15.5f) * 0.0625f), 0.f), 31.f);
    float t1f = fminf(fmaxf(floorf((bb.y - 0.5f) * 0.0625f), 0.f), 31.f);
    int tx0 = (int)t0f, tx1 = (int)t1f;
    if (tx0 > tx1) continue;
    const float4* rp = fdP + (bOff + f) * 3;
    float4 r0 = rp[0], r1 = rp[1], r2 = rp[2];
    int q = bucketOf(r2.w, zlo, iscale);
    for (int tx = tx0; tx <= tx1; ++tx) {
      float tX0 = 16.f * tx + 0.5f, tX1 = tX0 + 15.f;
      if (tileCull(r0, r1, tX0, tX1, tY0, tY1)) {
        if (FILL) {
          unsigned pos = atomicAdd(&lc[tx * kNB + q], 1u);
          if (pos < kListCap) list[pos] = (unsigned short)f;
        } else {
          atomicAdd(&lc[tx * kNB + q], 1u);
        }
      }
    }
  }
  __syncthreads();
  if (!FILL) cnt[gcell] = lc[t];
}

// In-place exclusive scan over the 65,536 (bin,chunk) counts; sentinel total
// at cnt[kNBins]. Single block; no per-thread arrays (reads each cell twice).
__global__ void scan_k(unsigned* __restrict__ cnt) {
  constexpr int PER = kNBins / 256;   // 256
  __shared__ unsigned part[256];
  __shared__ unsigned base_[256];
  int t = threadIdx.x;
  unsigned s = 0;
  for (int i = 0; i < PER; ++i) s += cnt[t * PER + i];
  part[t] = s;
  __syncthreads();
  if (t == 0) {
    unsigned r = 0;
    for (int i = 0; i < 256; ++i) { base_[i] = r; r += part[i]; }
  }
  __syncthreads();
  unsigned r = base_[t];
  for (int i = 0; i < PER; ++i) {
    unsigned v = cnt[t * PER + i];
    cnt[t * PER + i] = r;
    r += v;
  }
  if (t == 255) cnt[kNBins] = r;   // total
}

// 16x16-pixel tile per block; iterates its pre-binned candidate list bucket by
// bucket (front-to-back), LDS-staging 256 candidates at a time. Early-break
// when ALL pixels' zmin beats the conservative lower bound of later buckets.
// Discrete decisions replicate reference fp32 rounding; (z,idx) lex-min is
// order-independent == jnp.argmin first-min. Shading fused.
__global__ __launch_bounds__(256) void raster_k(
    const float4* __restrict__ fdP, const float4* __restrict__ fdE,
    const unsigned* __restrict__ off, const unsigned short* __restrict__ list,
    const unsigned* __restrict__ zr, const float* __restrict__ verts,
    const float* __restrict__ nrm, const int* __restrict__ faces,
    float* __restrict__ out) {
  __shared__ float4 sA[256], sB[256], sC[256];   // 12 KiB
  int b = blockIdx.z;
  size_t bOff = (size_t)b * kNF;
  int tx = threadIdx.x & 15, ty = threadIdx.x >> 4;
  int x = blockIdx.x * 16 + tx;
  int y = blockIdx.y * 16 + ty;
  float xp = (float)x + 0.5f;
  float yp = (float)y + 0.5f;
  bool live = (x < kW && y < kH);
  float zmin = live ? INFINITY : -INFINITY;   // dead px never block the break
  int best = 0x7FFFFFFF;
  float bw0 = 0.f, bw1 = 0.f, bw2 = 0.f;

  float zlo = __uint_as_float(zr[2 * b]);
  float zhi = __uint_as_float(zr[2 * b + 1]);
  float range = zhi - zlo;
  float bwid = range > 1e-30f ? range * (1.f / kNB) : 0.f;
  const unsigned* offT =
      off + (unsigned)((b * 32 + blockIdx.y) * 32 + blockIdx.x) * kNB * kChunks;

  for (int q = 0; q < kNB; ++q) {
    if (q > 0) {
      float lb = zlo + (float)q * bwid * (1.f - 1e-5f) - 2e-5f;
      if (__syncthreads_and(zmin < lb)) break;
    }
    unsigned s = offT[q * kChunks], e = offT[(q + 1) * kChunks];
    for (unsigned base = s; base < e; base += 256) {
      int n = min(256u, e - base);
      __syncthreads();
      if ((int)threadIdx.x < n) {
        unsigned fi = list[base + threadIdx.x];
        const float4* rp = fdP + (bOff + fi) * 3;
        float4 r0 = rp[0], r1 = rp[1], r2 = rp[2];
        r2.w = __int_as_float((int)fi);
        sA[threadIdx.x] = r0;
        sB[threadIdx.x] = r1;
        sC[threadIdx.x] = r2;
      }
      __syncthreads();
      for (int k = 0; k < n; ++k) {
        float4 a = sA[k], bq = sB[k], c = sC[k];
        float w0a = fmaf(a.x, xp, fmaf(a.y, yp, a.z));
        float w1a = fmaf(bq.x, xp, fmaf(bq.y, yp, bq.z));
        float w2a = 1.f - w0a - w1a;
        float zl = fmaf(c.x, xp, fmaf(c.y, yp, c.z));
        float wmin = fminf(fminf(w0a, w1a), w2a);
        if (wmin >= -a.w && zl <= zmin + bq.w) {
          int fi = __float_as_int(c.w);
          const float4* ep = fdE + (bOff + fi) * 3;
          float4 e0 = ep[0], e1 = ep[1], e2 = ep[2];
          float dx = __fsub_rn(xp, e0.x), dy = __fsub_rn(yp, e0.y);
          float num0 = __fadd_rn(__fmul_rn(e0.z, dx), __fmul_rn(e0.w, dy));
          float num1 = __fadd_rn(__fmul_rn(e1.x, dx), __fmul_rn(e1.y, dy));
          float w0 = __fdiv_rn(num0, e1.z);
          float w1 = __fdiv_rn(num1, e1.z);
          float w2 = __fsub_rn(__fsub_rn(1.f, w0), w1);
          if (w0 >= 0.f && w1 >= 0.f && w2 >= 0.f) {
            float z = __fadd_rn(
                __fadd_rn(__fmul_rn(w0, e1.w), __fmul_rn(w1, e2.x)),
                __fmul_rn(w2, e2.y));
            if (z < zmin || (z == zmin && fi < best)) {
              zmin = z; best = fi; bw0 = w0; bw1 = w1; bw2 = w2;
            }
          }
        }
      }
    }
  }

  if (!live) return;

  float rv, av;
  if (zmin < INFINITY) {
    int i0 = faces[3 * best + 0], i1 = faces[3 * best + 1], i2 = faces[3 * best + 2];
    const float* vb = verts + (size_t)b * kNV * 3;
    const float* nb = nrm + (size_t)b * kNV * 3;
    float px_ = bw0 * vb[3 * i0 + 0] + bw1 * vb[3 * i1 + 0] + bw2 * vb[3 * i2 + 0];
    float py_ = bw0 * vb[3 * i0 + 1] + bw1 * vb[3 * i1 + 1] + bw2 * vb[3 * i2 + 1];
    float pz_ = bw0 * vb[3 * i0 + 2] + bw1 * vb[3 * i1 + 2] + bw2 * vb[3 * i2 + 2];
    float nx = bw0 * nb[3 * i0 + 0] + bw1 * nb[3 * i1 + 0] + bw2 * nb[3 * i2 + 0];
    float ny = bw0 * nb[3 * i0 + 1] + bw1 * nb[3 * i1 + 1] + bw2 * nb[3 * i2 + 1];
    float nz = bw0 * nb[3 * i0 + 2] + bw1 * nb[3 * i1 + 2] + bw2 * nb[3 * i2 + 2];
    float nn = sqrtf(nx * nx + ny * ny + nz * nz);
    float nd = fmaxf(nn, kEps);
    nx /= nd; ny /= nd; nz /= nd;
    float pn = sqrtf(px_ * px_ + py_ * py_ + pz_ * pz_);
    float pd = fmaxf(pn, kEps);
    float lx = -px_ / pd, ly = -py_ / pd, lz = -pz_ / pd;
    float sdot = nx * lx + ny * ly + nz * lz;
    float ndl = fmaxf(sdot, 0.0f);
    float rx = 2.0f * sdot * nx - lx;
    float ry = 2.0f * sdot * ny - ly;
    float rz = 2.0f * sdot * nz - lz;
    float vdr = fmaxf(lx * rx + ly * ry + lz * rz, 0.0f);
    float qv = vdr;   // vdr^64 via 6 squarings
    qv = qv * qv; qv = qv * qv; qv = qv * qv;
    qv = qv * qv; qv = qv * qv; qv = qv * qv;
    float shade = 0.5f * (0.5f + 0.3f * ndl) + 0.2f * qv;
    rv = fminf(fmaxf(shade, 0.0f), 255.0f);
    av = 1.0f;
  } else {
    rv = 1.0f;
    av = 0.0f;
  }
  ((float4*)out)[((size_t)b * kH + y) * kW + x] = make_float4(rv, rv, rv, av);
}

}  // namespace

extern "C" void kernel_launch(void* const* d_in, const int* in_sizes, int n_in,
                              void* d_out, int out_size, void* d_ws, size_t ws_size,
                              hipStream_t stream) {
  (void)in_sizes; (void)n_in; (void)out_size; (void)ws_size;
  const float* verts = (const float*)d_in[0];   // (B, NV, 3) f32
  const int* faces = (const int*)d_in[1];       // (NF, 3) i32
  float* out = (float*)d_out;                   // (B, H, W, 4) f32
  float* ws = (float*)d_ws;

  // ws layout (float offsets; total ~6.45 MB, within proven ws >= 6.455 MB):
  //   nacc @ 0          (30,138)
  //   proj @ 30,720     (float4 x 10,046)
  //   fdE  @ 71,680     (float4 x 59,856)
  //   fdP  @ 311,296    (float4 x 59,856)
  //   fdB  @ 550,912    (float4 x 19,952)
  //   zr   @ 630,784    (u32 x 4)
  //   cnt  @ 630,912    (u32 x 65,537)  [doubles as scanned offsets]
  //   list @ 696,576    (u16 x 1,830,000)
  float* nacc = ws;
  float4* proj = (float4*)(ws + 30720);
  float4* fdE = (float4*)(ws + 71680);
  float4* fdP = (float4*)(ws + 311296);
  float4* fdB = (float4*)(ws + 550912);
  unsigned* zr = (unsigned*)(ws + 630784);
  unsigned* cnt = (unsigned*)(ws + 630912);
  unsigned short* list = (unsigned short*)(ws + 696576);

  hipLaunchKernelGGL(init_k, dim3(120), dim3(256), 0, stream, nacc, zr);
  hipLaunchKernelGGL(normal_accum_k, dim3((kB * kNF + 255) / 256), dim3(256), 0,
                     stream, verts, faces, nacc);
  hipLaunchKernelGGL(proj_norm_k, dim3((kB * kNV + 255) / 256), dim3(256), 0,
                     stream, verts, nacc, proj);
  hipLaunchKernelGGL(face_setup_k, dim3((kNF + 255) / 256, kB), dim3(256), 0,
                     stream, proj, faces, fdE, fdP, fdB, zr);
  hipLaunchKernelGGL((bin_k<false>), dim3(kChunks, 32, kB), dim3(256), 0,
                     stream, fdP, fdB, zr, cnt, list);
  hipLaunchKernelGGL(scan_k, dim3(1), dim3(256), 0, stream, cnt);
  hipLaunchKernelGGL((bin_k<true>), dim3(kChunks, 32, kB), dim3(256), 0,
                     stream, fdP, fdB, zr, cnt, list);
  hipLaunchKernelGGL(raster_k, dim3(32, 32, kB), dim3(256), 0, stream,
                     fdP, fdE, cnt, list, zr, verts, nacc, faces, out);
}